// Round 2
// baseline (1257.551 us; speedup 1.0000x reference)
//
#include <hip/hip_runtime.h>
#include <hip/hip_bf16.h>

#define NNODES 100000
#define NEDGES 1600000
#define CH 128
#define OUTC 40
#define BN_EPS 1e-5f

// ---------------- degree histogram ----------------
__global__ void k_deg(const int* __restrict__ dst, int* __restrict__ deg) {
    int e = blockIdx.x * blockDim.x + threadIdx.x;
    if (e < NEDGES) atomicAdd(&deg[dst[e]], 1);
}

// ---------------- exclusive scan (3-phase) ----------------
__global__ void k_scan1(const int* __restrict__ deg, int* __restrict__ row_ptr,
                        int* __restrict__ blkSums, float* __restrict__ inv_deg) {
    __shared__ int sd[256];
    int base = blockIdx.x * 1024 + threadIdx.x * 4;
    int t[4];
#pragma unroll
    for (int j = 0; j < 4; ++j) {
        int i = base + j;
        t[j] = (i < NNODES) ? deg[i] : 0;
        if (i < NNODES) inv_deg[i] = 1.0f / fmaxf((float)t[j], 1.0f);
    }
    int tsum = t[0] + t[1] + t[2] + t[3];
    sd[threadIdx.x] = tsum;
    __syncthreads();
    for (int off = 1; off < 256; off <<= 1) {
        int v = (threadIdx.x >= off) ? sd[threadIdx.x - off] : 0;
        __syncthreads();
        sd[threadIdx.x] += v;
        __syncthreads();
    }
    int run = sd[threadIdx.x] - tsum;  // exclusive prefix for this thread
#pragma unroll
    for (int j = 0; j < 4; ++j) {
        int i = base + j;
        if (i < NNODES) row_ptr[i] = run;
        run += t[j];
    }
    if (threadIdx.x == 255) blkSums[blockIdx.x] = sd[255];
}

__global__ void k_scan2(int* blkSums, int nb) {
    if (threadIdx.x == 0 && blockIdx.x == 0) {
        int run = 0;
        for (int b = 0; b < nb; ++b) { int v = blkSums[b]; blkSums[b] = run; run += v; }
    }
}

__global__ void k_scan3(int* __restrict__ row_ptr, int* __restrict__ cursor,
                        const int* __restrict__ blkSums) {
    int i = blockIdx.x * blockDim.x + threadIdx.x;
    if (i < NNODES) {
        int v = row_ptr[i] + blkSums[i >> 10];
        row_ptr[i] = v;
        cursor[i] = v;
    }
    if (i == 0) row_ptr[NNODES] = NEDGES;
}

__global__ void k_fill(const int* __restrict__ src, const int* __restrict__ dst,
                       int* __restrict__ cursor, int* __restrict__ sorted_src) {
    int e = blockIdx.x * blockDim.x + threadIdx.x;
    if (e < NEDGES) {
        int d = dst[e];
        int pos = atomicAdd(&cursor[d], 1);
        sorted_src[pos] = src[e];
    }
}

// ---------------- mean aggregation (CSR gather, 1 wave per node) ----------------
// BN=true: h_eff = relu(h*scale+shift) applied per element on the fly.
template <bool BN>
__global__ void k_aggregate(const float* __restrict__ h, const int* __restrict__ row_ptr,
                            const int* __restrict__ sorted_src, const float* __restrict__ inv_deg,
                            const float* __restrict__ bnscale, const float* __restrict__ bnshift,
                            float* __restrict__ agg) {
    int wave = threadIdx.x >> 6;
    int lane = threadIdx.x & 63;
    int node = blockIdx.x * 4 + wave;
    if (node >= NNODES) return;
    float2 sc = make_float2(1.f, 1.f), sh = make_float2(0.f, 0.f);
    if (BN) {
        sc = *(const float2*)&bnscale[lane * 2];
        sh = *(const float2*)&bnshift[lane * 2];
    }
    int s0 = row_ptr[node], s1 = row_ptr[node + 1];
    float ax = 0.f, ay = 0.f;
    const float2* hp = (const float2*)h;
    for (int e = s0; e < s1; ++e) {
        int s = sorted_src[e];
        float2 v = hp[(size_t)s * 64 + lane];
        if (BN) {
            v.x = fmaxf(fmaf(v.x, sc.x, sh.x), 0.f);
            v.y = fmaxf(fmaf(v.y, sc.y, sh.y), 0.f);
        }
        ax += v.x; ay += v.y;
    }
    float w = inv_deg[node];
    float2* ap = (float2*)agg;
    ap[(size_t)node * 64 + lane] = make_float2(ax * w, ay * w);
}

// ---------------- fused dual GEMM: z = agg@Wl + bias + f(hin)@Wr ----------------
// BN_A: apply relu(bn(.)) to hin during A-staging (agg half is already normalized).
// STATS: accumulate per-channel sum/sumsq of z into sums[0..NC-1], sums[128..].
// LSM: skip z store; apply row-wise log_softmax and write to z (the out buffer).
template <int NC, int WPAD, bool BN_A, bool STATS, bool LSM>
__global__ __launch_bounds__(256) void k_gemm(
    const float* __restrict__ agg, const float* __restrict__ hin,
    const float* __restrict__ Wl, const float* __restrict__ Wr,
    const float* __restrict__ bias,
    const float* __restrict__ bnscale, const float* __restrict__ bnshift,
    float* __restrict__ z, float* __restrict__ sums) {
    constexpr int CPT = (NC + 15) / 16;
    __shared__ float A_lds[128 * 36];
    __shared__ float W_lds[32 * WPAD];
    int tid = threadIdx.x;
    int ty = tid >> 4, tx = tid & 15;
    int row0 = blockIdx.x * 128;
    float acc[8][CPT];
#pragma unroll
    for (int i = 0; i < 8; ++i)
#pragma unroll
        for (int j = 0; j < CPT; ++j) acc[i][j] = 0.f;

    for (int half = 0; half < 2; ++half) {
        const float* Asrc = half ? hin : agg;
        const float* Wsrc = half ? Wr : Wl;
        for (int kc = 0; kc < CH; kc += 32) {
            __syncthreads();
            // stage A tile: 128 rows x 32 k (stride 36, float4-aligned)
#pragma unroll
            for (int q = 0; q < 4; ++q) {
                int r = (tid >> 3) + 32 * q;
                int c = (tid & 7) << 2;
                int gr = row0 + r;
                float4 v = make_float4(0.f, 0.f, 0.f, 0.f);
                if (gr < NNODES) v = *(const float4*)&Asrc[(size_t)gr * CH + kc + c];
                if (BN_A && half == 1) {
                    float4 s4 = *(const float4*)&bnscale[kc + c];
                    float4 h4 = *(const float4*)&bnshift[kc + c];
                    v.x = fmaxf(fmaf(v.x, s4.x, h4.x), 0.f);
                    v.y = fmaxf(fmaf(v.y, s4.y, h4.y), 0.f);
                    v.z = fmaxf(fmaf(v.z, s4.z, h4.z), 0.f);
                    v.w = fmaxf(fmaf(v.w, s4.w, h4.w), 0.f);
                }
                *(float4*)&A_lds[r * 36 + c] = v;
            }
            // stage W tile: 32 x NC (zero-pad to WPAD)
            for (int idx = tid; idx < 32 * WPAD; idx += 256) {
                int k = idx / WPAD, c = idx - k * WPAD;
                W_lds[idx] = (c < NC) ? Wsrc[(kc + k) * NC + c] : 0.f;
            }
            __syncthreads();
#pragma unroll 8
            for (int k = 0; k < 32; ++k) {
                float a[8];
#pragma unroll
                for (int i = 0; i < 8; ++i) a[i] = A_lds[(ty + 16 * i) * 36 + k];
                float wv[CPT];
#pragma unroll
                for (int j = 0; j < CPT; ++j) wv[j] = W_lds[k * WPAD + tx + 16 * j];
#pragma unroll
                for (int i = 0; i < 8; ++i)
#pragma unroll
                    for (int j = 0; j < CPT; ++j) acc[i][j] = fmaf(a[i], wv[j], acc[i][j]);
            }
        }
    }

    // add bias into acc
    float bcol[CPT];
#pragma unroll
    for (int j = 0; j < CPT; ++j) {
        int c = tx + 16 * j;
        bcol[j] = (c < NC) ? bias[c] : 0.f;
    }
#pragma unroll
    for (int i = 0; i < 8; ++i)
#pragma unroll
        for (int j = 0; j < CPT; ++j) acc[i][j] += bcol[j];

    if (!LSM) {
#pragma unroll
        for (int i = 0; i < 8; ++i) {
            int gr = row0 + ty + 16 * i;
            if (gr >= NNODES) continue;
#pragma unroll
            for (int j = 0; j < CPT; ++j) {
                int c = tx + 16 * j;
                if (c < NC) z[(size_t)gr * NC + c] = acc[i][j];
            }
        }
    }

    if (STATS) {
        __shared__ float smem_s[4][128];
        __shared__ float smem_q[4][128];
        float s[CPT], q[CPT];
#pragma unroll
        for (int j = 0; j < CPT; ++j) { s[j] = 0.f; q[j] = 0.f; }
#pragma unroll
        for (int i = 0; i < 8; ++i) {
            int gr = row0 + ty + 16 * i;
            if (gr < NNODES) {
#pragma unroll
                for (int j = 0; j < CPT; ++j) {
                    float a = acc[i][j];
                    s[j] += a; q[j] += a * a;
                }
            }
        }
        // reduce across the 4 ty values within each wave (lane bits 4..5)
#pragma unroll
        for (int j = 0; j < CPT; ++j) {
            s[j] += __shfl_xor(s[j], 16); q[j] += __shfl_xor(q[j], 16);
            s[j] += __shfl_xor(s[j], 32); q[j] += __shfl_xor(q[j], 32);
        }
        int wv = tid >> 6, lane = tid & 63;
        if (lane < 16) {
#pragma unroll
            for (int j = 0; j < CPT; ++j) {
                smem_s[wv][lane + 16 * j] = s[j];
                smem_q[wv][lane + 16 * j] = q[j];
            }
        }
        __syncthreads();
        if (tid < NC) {
            atomicAdd(&sums[tid], smem_s[0][tid] + smem_s[1][tid] + smem_s[2][tid] + smem_s[3][tid]);
        } else if (tid >= 128 && tid < 128 + NC) {
            int c = tid - 128;
            atomicAdd(&sums[128 + c], smem_q[0][c] + smem_q[1][c] + smem_q[2][c] + smem_q[3][c]);
        }
    }

    if (LSM) {
        // row-wise log_softmax; row r lives in 16 contiguous lanes (tx=0..15)
#pragma unroll
        for (int i = 0; i < 8; ++i) {
            int gr = row0 + ty + 16 * i;
            if (gr >= NNODES) continue;
            float m = -INFINITY;
#pragma unroll
            for (int j = 0; j < CPT; ++j)
                if (tx + 16 * j < NC) m = fmaxf(m, acc[i][j]);
            m = fmaxf(m, __shfl_xor(m, 1));
            m = fmaxf(m, __shfl_xor(m, 2));
            m = fmaxf(m, __shfl_xor(m, 4));
            m = fmaxf(m, __shfl_xor(m, 8));
            float se = 0.f;
#pragma unroll
            for (int j = 0; j < CPT; ++j)
                if (tx + 16 * j < NC) se += expf(acc[i][j] - m);
            se += __shfl_xor(se, 1);
            se += __shfl_xor(se, 2);
            se += __shfl_xor(se, 4);
            se += __shfl_xor(se, 8);
            float lse = m + logf(se);
#pragma unroll
            for (int j = 0; j < CPT; ++j) {
                int c = tx + 16 * j;
                if (c < NC) z[(size_t)gr * NC + c] = acc[i][j] - lse;
            }
        }
    }
}

// ---------------- BN finalize: scale/shift from sums ----------------
__global__ void k_bn_finalize(const float* __restrict__ sums, const float* __restrict__ g,
                              const float* __restrict__ be, float* __restrict__ scale,
                              float* __restrict__ shift) {
    int c = threadIdx.x;
    if (c < CH) {
        float mean = sums[c] * (1.0f / NNODES);
        float var = sums[128 + c] * (1.0f / NNODES) - mean * mean;
        float sc = g[c] * rsqrtf(var + BN_EPS);
        scale[c] = sc;
        shift[c] = be[c] - mean * sc;
    }
}

extern "C" void kernel_launch(void* const* d_in, const int* in_sizes, int n_in,
                              void* d_out, int out_size, void* d_ws, size_t ws_size,
                              hipStream_t stream) {
    const float* x   = (const float*)d_in[0];
    const int* esrc  = (const int*)d_in[1];
    const int* edst  = (const int*)d_in[2];
    const float* W_l0 = (const float*)d_in[3];
    const float* b_l0 = (const float*)d_in[4];
    const float* W_r0 = (const float*)d_in[5];
    const float* g0   = (const float*)d_in[6];
    const float* be0  = (const float*)d_in[7];
    const float* W_l1 = (const float*)d_in[8];
    const float* b_l1 = (const float*)d_in[9];
    const float* W_r1 = (const float*)d_in[10];
    const float* g1   = (const float*)d_in[11];
    const float* be1  = (const float*)d_in[12];
    const float* W_l2 = (const float*)d_in[13];
    const float* b_l2 = (const float*)d_in[14];
    const float* W_r2 = (const float*)d_in[15];
    float* out = (float*)d_out;

    char* w = (char*)d_ws;
    size_t o = 0;
    auto nxt = [&](size_t b) { void* p = w + o; o = (o + b + 511) & ~(size_t)511; return p; };
    int* deg      = (int*)nxt((size_t)NNODES * 4);
    int* row_ptr  = (int*)nxt((size_t)(NNODES + 1) * 4);
    int* cursor   = (int*)nxt((size_t)NNODES * 4);
    float* invdeg = (float*)nxt((size_t)NNODES * 4);
    int* blkSums  = (int*)nxt(128 * 4);
    float* sums   = (float*)nxt(512 * 4);   // sums0[256] | sums1[256]
    float* scsh   = (float*)nxt(512 * 4);   // scale0, shift0, scale1, shift1
    int* sorted   = (int*)nxt((size_t)NEDGES * 4);
    float* agg    = (float*)nxt((size_t)NNODES * CH * 4);
    float* z0     = (float*)nxt((size_t)NNODES * CH * 4);
    float* z1     = (float*)nxt((size_t)NNODES * CH * 4);
    float* sums0 = sums, *sums1 = sums + 256;
    float* scale0 = scsh, *shift0 = scsh + 128, *scale1 = scsh + 256, *shift1 = scsh + 384;

    hipMemsetAsync(deg, 0, (size_t)NNODES * 4, stream);
    hipMemsetAsync(sums, 0, 512 * 4, stream);

    const int EB = (NEDGES + 255) / 256;
    const int SCAN_B = (NNODES + 1023) / 1024;  // 98
    const int NB = (NNODES + 255) / 256;
    const int AGG_B = (NNODES + 3) / 4;
    const int GEMM_B = (NNODES + 127) / 128;

    // CSR build
    k_deg<<<EB, 256, 0, stream>>>(edst, deg);
    k_scan1<<<SCAN_B, 256, 0, stream>>>(deg, row_ptr, blkSums, invdeg);
    k_scan2<<<1, 64, 0, stream>>>(blkSums, SCAN_B);
    k_scan3<<<NB, 256, 0, stream>>>(row_ptr, cursor, blkSums);
    k_fill<<<EB, 256, 0, stream>>>(esrc, edst, cursor, sorted);

    // layer 0: agg(x) -> z0 (+stats) -> scale/shift
    k_aggregate<false><<<AGG_B, 256, 0, stream>>>(x, row_ptr, sorted, invdeg,
                                                  nullptr, nullptr, agg);
    k_gemm<128, 132, false, true, false><<<GEMM_B, 256, 0, stream>>>(
        agg, x, W_l0, W_r0, b_l0, nullptr, nullptr, z0, sums0);
    k_bn_finalize<<<1, 128, 0, stream>>>(sums0, g0, be0, scale0, shift0);

    // layer 1: agg(relu(bn(z0))) -> z1 (+stats)
    k_aggregate<true><<<AGG_B, 256, 0, stream>>>(z0, row_ptr, sorted, invdeg,
                                                 scale0, shift0, agg);
    k_gemm<128, 132, true, true, false><<<GEMM_B, 256, 0, stream>>>(
        agg, z0, W_l1, W_r1, b_l1, scale0, shift0, z1, sums1);
    k_bn_finalize<<<1, 128, 0, stream>>>(sums1, g1, be1, scale1, shift1);

    // layer 2: agg(relu(bn(z1))) -> fused log_softmax -> out
    k_aggregate<true><<<AGG_B, 256, 0, stream>>>(z1, row_ptr, sorted, invdeg,
                                                 scale1, shift1, agg);
    k_gemm<40, 48, true, false, true><<<GEMM_B, 256, 0, stream>>>(
        agg, z1, W_l2, W_r2, b_l2, scale1, shift1, out, nullptr);
}

// Round 3
// 1049.778 us; speedup vs baseline: 1.1979x; 1.1979x over previous
//
#include <hip/hip_runtime.h>
#include <hip/hip_bf16.h>

#define NNODES 100000
#define NEDGES 1600000
#define CH 128
#define OUTC 40
#define BN_EPS 1e-5f

// ---------------- degree histogram ----------------
__global__ void k_deg(const int* __restrict__ dst, int* __restrict__ deg) {
    int e = blockIdx.x * blockDim.x + threadIdx.x;
    if (e < NEDGES) atomicAdd(&deg[dst[e]], 1);
}

// ---------------- exclusive scan (3-phase) ----------------
__global__ void k_scan1(const int* __restrict__ deg, int* __restrict__ row_ptr,
                        int* __restrict__ blkSums, float* __restrict__ inv_deg) {
    __shared__ int sd[256];
    int base = blockIdx.x * 1024 + threadIdx.x * 4;
    int t[4];
#pragma unroll
    for (int j = 0; j < 4; ++j) {
        int i = base + j;
        t[j] = (i < NNODES) ? deg[i] : 0;
        if (i < NNODES) inv_deg[i] = 1.0f / fmaxf((float)t[j], 1.0f);
    }
    int tsum = t[0] + t[1] + t[2] + t[3];
    sd[threadIdx.x] = tsum;
    __syncthreads();
    for (int off = 1; off < 256; off <<= 1) {
        int v = (threadIdx.x >= off) ? sd[threadIdx.x - off] : 0;
        __syncthreads();
        sd[threadIdx.x] += v;
        __syncthreads();
    }
    int run = sd[threadIdx.x] - tsum;  // exclusive prefix for this thread
#pragma unroll
    for (int j = 0; j < 4; ++j) {
        int i = base + j;
        if (i < NNODES) row_ptr[i] = run;
        run += t[j];
    }
    if (threadIdx.x == 255) blkSums[blockIdx.x] = sd[255];
}

__global__ void k_scan2(int* blkSums, int nb) {
    if (threadIdx.x == 0 && blockIdx.x == 0) {
        int run = 0;
        for (int b = 0; b < nb; ++b) { int v = blkSums[b]; blkSums[b] = run; run += v; }
    }
}

__global__ void k_scan3(int* __restrict__ row_ptr, int* __restrict__ cursor,
                        const int* __restrict__ blkSums) {
    int i = blockIdx.x * blockDim.x + threadIdx.x;
    if (i < NNODES) {
        int v = row_ptr[i] + blkSums[i >> 10];
        row_ptr[i] = v;
        cursor[i] = v;
    }
    if (i == 0) row_ptr[NNODES] = NEDGES;
}

__global__ void k_fill(const int* __restrict__ src, const int* __restrict__ dst,
                       int* __restrict__ cursor, int* __restrict__ sorted_src) {
    int e = blockIdx.x * blockDim.x + threadIdx.x;
    if (e < NEDGES) {
        int d = dst[e];
        int pos = atomicAdd(&cursor[d], 1);
        sorted_src[pos] = src[e];
    }
}

// ---------------- dual GEMM: yl = f(h)@Wl ; yr = f(h)@Wr + bias ----------------
// f(.) = relu(bn(.)) if BN_A.  A tile staged once per (half,kchunk); acc reused
// across halves (stored to yl after half 0, yr after half 1).
// Threads: ty=tid>>4 (rows ty+16i, i<8), tx=tid&15 (cols tx*4 [+64 if NC=128]).
// All LDS traffic is ds_read_b128 / ds_write_b128.
template <int NC, int WP, bool BN_A>
__global__ __launch_bounds__(256) void k_gemm2(
    const float* __restrict__ h,
    const float* __restrict__ Wl, const float* __restrict__ Wr,
    const float* __restrict__ bias,
    const float* __restrict__ bnscale, const float* __restrict__ bnshift,
    float* __restrict__ yl, float* __restrict__ yr) {
    constexpr int NG = (NC == 128) ? 2 : 1;  // float4 col-groups per thread
    constexpr int WSLOTS = NC / 4;           // real float4 slots per W row
    __shared__ float A_lds[128 * 36];
    __shared__ float W_lds[32 * WP];
    int tid = threadIdx.x;
    int ty = tid >> 4, tx = tid & 15;
    int row0 = blockIdx.x * 128;

    for (int half = 0; half < 2; ++half) {
        const float* W = half ? Wr : Wl;
        float acc[8][NG * 4];
#pragma unroll
        for (int i = 0; i < 8; ++i)
#pragma unroll
            for (int j = 0; j < NG * 4; ++j) acc[i][j] = 0.f;

        for (int kc = 0; kc < CH; kc += 32) {
            __syncthreads();
            // stage A tile 128x32 (row stride 36, float4 aligned)
#pragma unroll
            for (int q = 0; q < 4; ++q) {
                int r = (tid >> 3) + 32 * q;
                int c = (tid & 7) << 2;
                int gr = row0 + r;
                float4 v = make_float4(0.f, 0.f, 0.f, 0.f);
                if (gr < NNODES) v = *(const float4*)&h[(size_t)gr * CH + kc + c];
                if (BN_A) {
                    float4 s4 = *(const float4*)&bnscale[kc + c];
                    float4 h4 = *(const float4*)&bnshift[kc + c];
                    v.x = fmaxf(fmaf(v.x, s4.x, h4.x), 0.f);
                    v.y = fmaxf(fmaf(v.y, s4.y, h4.y), 0.f);
                    v.z = fmaxf(fmaf(v.z, s4.z, h4.z), 0.f);
                    v.w = fmaxf(fmaf(v.w, s4.w, h4.w), 0.f);
                }
                *(float4*)&A_lds[r * 36 + c] = v;
            }
            // stage W tile 32 x NC as float4 slots
            for (int idx = tid; idx < 32 * WSLOTS; idx += 256) {
                int k = idx / WSLOTS, s = idx - k * WSLOTS;
                *(float4*)&W_lds[k * WP + s * 4] = *(const float4*)&W[(size_t)(kc + k) * NC + s * 4];
            }
            __syncthreads();
#pragma unroll
            for (int k4 = 0; k4 < 32; k4 += 4) {
                float4 a4[8];
#pragma unroll
                for (int i = 0; i < 8; ++i)
                    a4[i] = *(const float4*)&A_lds[(ty + 16 * i) * 36 + k4];
#pragma unroll
                for (int kk = 0; kk < 4; ++kk) {
                    float4 w0 = *(const float4*)&W_lds[(k4 + kk) * WP + tx * 4];
                    float4 w1;
                    if (NG == 2) w1 = *(const float4*)&W_lds[(k4 + kk) * WP + 64 + tx * 4];
#pragma unroll
                    for (int i = 0; i < 8; ++i) {
                        float av = (&a4[i].x)[kk];
                        acc[i][0] = fmaf(av, w0.x, acc[i][0]);
                        acc[i][1] = fmaf(av, w0.y, acc[i][1]);
                        acc[i][2] = fmaf(av, w0.z, acc[i][2]);
                        acc[i][3] = fmaf(av, w0.w, acc[i][3]);
                        if (NG == 2) {
                            acc[i][4] = fmaf(av, w1.x, acc[i][4]);
                            acc[i][5] = fmaf(av, w1.y, acc[i][5]);
                            acc[i][6] = fmaf(av, w1.z, acc[i][6]);
                            acc[i][7] = fmaf(av, w1.w, acc[i][7]);
                        }
                    }
                }
            }
        }
        // epilogue: store this half (bias only on yr)
        float* Y = half ? yr : yl;
        bool colok = (NC != 40) || (tx < 10);
        float4 b0 = make_float4(0.f, 0.f, 0.f, 0.f), b1 = b0;
        if (half == 1 && colok) {
            b0 = *(const float4*)&bias[tx * 4];
            if (NG == 2) b1 = *(const float4*)&bias[64 + tx * 4];
        }
#pragma unroll
        for (int i = 0; i < 8; ++i) {
            int gr = row0 + ty + 16 * i;
            if (gr >= NNODES || !colok) continue;
            float4 v0 = make_float4(acc[i][0] + b0.x, acc[i][1] + b0.y,
                                    acc[i][2] + b0.z, acc[i][3] + b0.w);
            *(float4*)&Y[(size_t)gr * NC + tx * 4] = v0;
            if (NG == 2) {
                float4 v1 = make_float4(acc[i][4] + b1.x, acc[i][5] + b1.y,
                                        acc[i][6] + b1.z, acc[i][7] + b1.w);
                *(float4*)&Y[(size_t)gr * NC + 64 + tx * 4] = v1;
            }
        }
    }
}

// ---------------- combine (NC=128): z[n] += invdeg[n] * sum yl[src] ----------------
__global__ void k_combine128(const float* __restrict__ yl, const int* __restrict__ row_ptr,
                             const int* __restrict__ sorted_src, const float* __restrict__ inv_deg,
                             float* __restrict__ z) {
    int wave = threadIdx.x >> 6, lane = threadIdx.x & 63;
    int node = blockIdx.x * 4 + wave;
    if (node >= NNODES) return;
    int s0 = row_ptr[node], s1 = row_ptr[node + 1];
    const float2* Y = (const float2*)yl;
    float ax0 = 0.f, ay0 = 0.f, ax1 = 0.f, ay1 = 0.f;
    float ax2 = 0.f, ay2 = 0.f, ax3 = 0.f, ay3 = 0.f;
    int e = s0;
    for (; e + 4 <= s1; e += 4) {
        int i0 = sorted_src[e], i1 = sorted_src[e + 1];
        int i2 = sorted_src[e + 2], i3 = sorted_src[e + 3];
        float2 v0 = Y[(size_t)i0 * 64 + lane];
        float2 v1 = Y[(size_t)i1 * 64 + lane];
        float2 v2 = Y[(size_t)i2 * 64 + lane];
        float2 v3 = Y[(size_t)i3 * 64 + lane];
        ax0 += v0.x; ay0 += v0.y; ax1 += v1.x; ay1 += v1.y;
        ax2 += v2.x; ay2 += v2.y; ax3 += v3.x; ay3 += v3.y;
    }
    for (; e < s1; ++e) {
        int i = sorted_src[e];
        float2 v = Y[(size_t)i * 64 + lane];
        ax0 += v.x; ay0 += v.y;
    }
    float w = inv_deg[node];
    float2* Z = (float2*)z;
    float2 r = Z[(size_t)node * 64 + lane];
    r.x += (ax0 + ax1 + ax2 + ax3) * w;
    r.y += (ay0 + ay1 + ay2 + ay3) * w;
    Z[(size_t)node * 64 + lane] = r;
}

// ---------------- combine (NC=40) + log_softmax -> out ----------------
__global__ void k_combine40_lsm(const float* __restrict__ yl, const float* __restrict__ yr,
                                const int* __restrict__ row_ptr, const int* __restrict__ sorted_src,
                                const float* __restrict__ inv_deg, float* __restrict__ out) {
    int wave = threadIdx.x >> 6, lane = threadIdx.x & 63;
    int node = blockIdx.x * 4 + wave;
    if (node >= NNODES) return;
    bool act = lane < 20;
    int s0 = row_ptr[node], s1 = row_ptr[node + 1];
    float ax0 = 0.f, ay0 = 0.f, ax1 = 0.f, ay1 = 0.f;
    float ax2 = 0.f, ay2 = 0.f, ax3 = 0.f, ay3 = 0.f;
    int e = s0;
    for (; e + 4 <= s1; e += 4) {
        int i0 = sorted_src[e], i1 = sorted_src[e + 1];
        int i2 = sorted_src[e + 2], i3 = sorted_src[e + 3];
        if (act) {
            float2 v0 = *(const float2*)&yl[(size_t)i0 * OUTC + lane * 2];
            float2 v1 = *(const float2*)&yl[(size_t)i1 * OUTC + lane * 2];
            float2 v2 = *(const float2*)&yl[(size_t)i2 * OUTC + lane * 2];
            float2 v3 = *(const float2*)&yl[(size_t)i3 * OUTC + lane * 2];
            ax0 += v0.x; ay0 += v0.y; ax1 += v1.x; ay1 += v1.y;
            ax2 += v2.x; ay2 += v2.y; ax3 += v3.x; ay3 += v3.y;
        }
    }
    for (; e < s1; ++e) {
        int i = sorted_src[e];
        if (act) {
            float2 v = *(const float2*)&yl[(size_t)i * OUTC + lane * 2];
            ax0 += v.x; ay0 += v.y;
        }
    }
    float zx = 0.f, zy = 0.f;
    if (act) {
        float w = inv_deg[node];
        float2 r = *(const float2*)&yr[(size_t)node * OUTC + lane * 2];
        zx = (ax0 + ax1 + ax2 + ax3) * w + r.x;
        zy = (ay0 + ay1 + ay2 + ay3) * w + r.y;
    }
    float m = act ? fmaxf(zx, zy) : -INFINITY;
#pragma unroll
    for (int off = 1; off <= 16; off <<= 1) m = fmaxf(m, __shfl_xor(m, off));
    float se = act ? (expf(zx - m) + expf(zy - m)) : 0.f;
#pragma unroll
    for (int off = 1; off <= 16; off <<= 1) se += __shfl_xor(se, off);
    float lse = m + logf(se);
    if (act) {
        float2 o = make_float2(zx - lse, zy - lse);
        *(float2*)&out[(size_t)node * OUTC + lane * 2] = o;
    }
}

// ---------------- BN batch stats (sum, sumsq per channel) ----------------
__global__ void k_stats(const float* __restrict__ h, float* __restrict__ sums) {
    __shared__ float ls[256], ls2[256];
    int c = threadIdx.x & 127;
    int half = threadIdx.x >> 7;
    float s = 0.f, s2 = 0.f;
    for (int r = blockIdx.x * 2 + half; r < NNODES; r += gridDim.x * 2) {
        float v = h[(size_t)r * CH + c];
        s += v; s2 += v * v;
    }
    ls[threadIdx.x] = s; ls2[threadIdx.x] = s2;
    __syncthreads();
    if (half == 0) {
        atomicAdd(&sums[c], ls[c] + ls[c + 128]);
        atomicAdd(&sums[CH + c], ls2[c] + ls2[c + 128]);
    }
}

__global__ void k_bn_finalize(const float* __restrict__ sums, const float* __restrict__ g,
                              const float* __restrict__ be, float* __restrict__ scale,
                              float* __restrict__ shift) {
    int c = threadIdx.x;
    if (c < CH) {
        float mean = sums[c] * (1.0f / NNODES);
        float var = sums[128 + c] * (1.0f / NNODES) - mean * mean;
        float sc = g[c] * rsqrtf(var + BN_EPS);
        scale[c] = sc;
        shift[c] = be[c] - mean * sc;
    }
}

extern "C" void kernel_launch(void* const* d_in, const int* in_sizes, int n_in,
                              void* d_out, int out_size, void* d_ws, size_t ws_size,
                              hipStream_t stream) {
    const float* x   = (const float*)d_in[0];
    const int* esrc  = (const int*)d_in[1];
    const int* edst  = (const int*)d_in[2];
    const float* W_l0 = (const float*)d_in[3];
    const float* b_l0 = (const float*)d_in[4];
    const float* W_r0 = (const float*)d_in[5];
    const float* g0   = (const float*)d_in[6];
    const float* be0  = (const float*)d_in[7];
    const float* W_l1 = (const float*)d_in[8];
    const float* b_l1 = (const float*)d_in[9];
    const float* W_r1 = (const float*)d_in[10];
    const float* g1   = (const float*)d_in[11];
    const float* be1  = (const float*)d_in[12];
    const float* W_l2 = (const float*)d_in[13];
    const float* b_l2 = (const float*)d_in[14];
    const float* W_r2 = (const float*)d_in[15];
    float* out = (float*)d_out;

    char* w = (char*)d_ws;
    size_t o = 0;
    auto nxt = [&](size_t b) { void* p = w + o; o = (o + b + 511) & ~(size_t)511; return p; };
    int* deg      = (int*)nxt((size_t)NNODES * 4);
    int* row_ptr  = (int*)nxt((size_t)(NNODES + 1) * 4);
    int* cursor   = (int*)nxt((size_t)NNODES * 4);
    float* invdeg = (float*)nxt((size_t)NNODES * 4);
    int* blkSums  = (int*)nxt(128 * 4);
    float* sums   = (float*)nxt(512 * 4);   // sums0[256] | sums1[256]
    float* scsh   = (float*)nxt(512 * 4);   // scale0, shift0, scale1, shift1
    int* sorted   = (int*)nxt((size_t)NEDGES * 4);
    float* ylbuf  = (float*)nxt((size_t)NNODES * CH * 4);
    float* zA     = (float*)nxt((size_t)NNODES * CH * 4);  // z0, later yr2
    float* zB     = (float*)nxt((size_t)NNODES * CH * 4);  // z1
    float* sums0 = sums, *sums1 = sums + 256;
    float* scale0 = scsh, *shift0 = scsh + 128, *scale1 = scsh + 256, *shift1 = scsh + 384;

    hipMemsetAsync(deg, 0, (size_t)NNODES * 4, stream);
    hipMemsetAsync(sums, 0, 512 * 4, stream);

    const int EB = (NEDGES + 255) / 256;
    const int SCAN_B = (NNODES + 1023) / 1024;  // 98
    const int NB = (NNODES + 255) / 256;
    const int COMB_B = (NNODES + 3) / 4;
    const int GEMM_B = (NNODES + 127) / 128;

    // CSR build
    k_deg<<<EB, 256, 0, stream>>>(edst, deg);
    k_scan1<<<SCAN_B, 256, 0, stream>>>(deg, row_ptr, blkSums, invdeg);
    k_scan2<<<1, 64, 0, stream>>>(blkSums, SCAN_B);
    k_scan3<<<NB, 256, 0, stream>>>(row_ptr, cursor, blkSums);
    k_fill<<<EB, 256, 0, stream>>>(esrc, edst, cursor, sorted);

    // layer 0: yl = x@Wl0, zA = x@Wr0 + b_l0; zA += invdeg*gather(yl); stats
    k_gemm2<128, 132, false><<<GEMM_B, 256, 0, stream>>>(
        x, W_l0, W_r0, b_l0, nullptr, nullptr, ylbuf, zA);
    k_combine128<<<COMB_B, 256, 0, stream>>>(ylbuf, row_ptr, sorted, invdeg, zA);
    k_stats<<<256, 256, 0, stream>>>(zA, sums0);
    k_bn_finalize<<<1, 128, 0, stream>>>(sums0, g0, be0, scale0, shift0);

    // layer 1: h1 = relu(bn(zA)) applied in staging
    k_gemm2<128, 132, true><<<GEMM_B, 256, 0, stream>>>(
        zA, W_l1, W_r1, b_l1, scale0, shift0, ylbuf, zB);
    k_combine128<<<COMB_B, 256, 0, stream>>>(ylbuf, row_ptr, sorted, invdeg, zB);
    k_stats<<<256, 256, 0, stream>>>(zB, sums1);
    k_bn_finalize<<<1, 128, 0, stream>>>(sums1, g1, be1, scale1, shift1);

    // layer 2: h2 = relu(bn(zB)); yl2 (N x 40) in ylbuf, yr2 in zA; combine+lsm
    k_gemm2<40, 64, true><<<GEMM_B, 256, 0, stream>>>(
        zB, W_l2, W_r2, b_l2, scale1, shift1, ylbuf, zA);
    k_combine40_lsm<<<COMB_B, 256, 0, stream>>>(ylbuf, zA, row_ptr, sorted, invdeg, out);
}

// Round 7
// 1009.810 us; speedup vs baseline: 1.2453x; 1.0396x over previous
//
#include <hip/hip_runtime.h>
#include <hip/hip_bf16.h>

#define NNODES 100000
#define NEDGES 1600000
#define CH 128
#define OUTC 40
#define BN_EPS 1e-5f

typedef __attribute__((ext_vector_type(8))) short s8v;    // 8 bf16 (4 VGPR)
typedef __attribute__((ext_vector_type(4))) float f32x4;  // MFMA acc

__device__ inline unsigned short f2bf_rn(float f) {
    unsigned u = __float_as_uint(f);
    return (unsigned short)((u + 0x7FFFu + ((u >> 16) & 1u)) >> 16);
}
__device__ inline float bf2f(unsigned short b) {
    return __uint_as_float((unsigned)b << 16);
}

// ---------------- degree histogram ----------------
__global__ void k_deg(const int* __restrict__ dst, int* __restrict__ deg) {
    int e = blockIdx.x * blockDim.x + threadIdx.x;
    if (e < NEDGES) atomicAdd(&deg[dst[e]], 1);
}

// ---------------- exclusive scan (3-phase) ----------------
__global__ void k_scan1(const int* __restrict__ deg, int* __restrict__ row_ptr,
                        int* __restrict__ blkSums, float* __restrict__ inv_deg) {
    __shared__ int sd[256];
    int base = blockIdx.x * 1024 + threadIdx.x * 4;
    int t[4];
#pragma unroll
    for (int j = 0; j < 4; ++j) {
        int i = base + j;
        t[j] = (i < NNODES) ? deg[i] : 0;
        if (i < NNODES) inv_deg[i] = 1.0f / fmaxf((float)t[j], 1.0f);
    }
    int tsum = t[0] + t[1] + t[2] + t[3];
    sd[threadIdx.x] = tsum;
    __syncthreads();
    for (int off = 1; off < 256; off <<= 1) {
        int v = (threadIdx.x >= off) ? sd[threadIdx.x - off] : 0;
        __syncthreads();
        sd[threadIdx.x] += v;
        __syncthreads();
    }
    int run = sd[threadIdx.x] - tsum;
#pragma unroll
    for (int j = 0; j < 4; ++j) {
        int i = base + j;
        if (i < NNODES) row_ptr[i] = run;
        run += t[j];
    }
    if (threadIdx.x == 255) blkSums[blockIdx.x] = sd[255];
}

__global__ void k_scan2(int* blkSums, int nb) {
    if (threadIdx.x == 0 && blockIdx.x == 0) {
        int run = 0;
        for (int b = 0; b < nb; ++b) { int v = blkSums[b]; blkSums[b] = run; run += v; }
    }
}

__global__ void k_scan3(int* __restrict__ row_ptr, int* __restrict__ cursor,
                        const int* __restrict__ blkSums) {
    int i = blockIdx.x * blockDim.x + threadIdx.x;
    if (i < NNODES) {
        int v = row_ptr[i] + blkSums[i >> 10];
        row_ptr[i] = v;
        cursor[i] = v;
    }
    if (i == 0) row_ptr[NNODES] = NEDGES;
}

__global__ void k_fill(const int* __restrict__ src, const int* __restrict__ dst,
                       int* __restrict__ cursor, int* __restrict__ sorted_src) {
    int e = blockIdx.x * blockDim.x + threadIdx.x;
    if (e < NEDGES) {
        int d = dst[e];
        int pos = atomicAdd(&cursor[d], 1);
        sorted_src[pos] = src[e];
    }
}

// ---------------- W prep: transpose + hi/lo bf16 split (once per call) ----------------
// wt layout (shorts): [0]=L0l hi16384,lo16384 | [32768]=L0r | [65536]=L1l |
// [98304]=L1r | [131072]=L2l hi6144,lo6144 | [143360]=L2r. WtX[col*128+k].
__global__ void k_prepw(const float* __restrict__ Wl0, const float* __restrict__ Wr0,
                        const float* __restrict__ Wl1, const float* __restrict__ Wr1,
                        const float* __restrict__ Wl2, const float* __restrict__ Wr2,
                        short* __restrict__ wt) {
    int gid = blockIdx.x * 256 + threadIdx.x;
    const float* W;
    int col, k, base, halfsz;
    float val;
    if (gid < 65536) {
        int w = gid >> 14;
        int r = gid & 16383;
        col = r >> 7; k = r & 127;
        W = (w == 0) ? Wl0 : (w == 1) ? Wr0 : (w == 2) ? Wl1 : Wr1;
        val = W[k * 128 + col];
        base = w * 32768; halfsz = 16384;
    } else if (gid < 77824) {
        int r2 = gid - 65536;
        int w = r2 / 6144;
        int r = r2 - w * 6144;
        col = r >> 7; k = r & 127;
        W = w ? Wr2 : Wl2;
        val = (col < OUTC) ? W[k * OUTC + col] : 0.f;
        base = 131072 + w * 12288; halfsz = 6144;
    } else {
        return;
    }
    unsigned short hi = f2bf_rn(val);
    unsigned short lo = f2bf_rn(val - bf2f(hi));
    int idx = col * 128 + k;
    wt[base + idx] = (short)hi;
    wt[base + halfsz + idx] = (short)lo;
}

// ---------------- MFMA dual GEMM (bf16x3): yl = f(H)@Wl ; yr = f(H)@Wr + b ----
// f(.) = relu(bn(.)) if BN_A. 128 rows/block, full K=128 staged once (hi/lo,
// XOR-swizzled: elem ^= (row&7)<<3 — G4 fix for 256B row stride).
// WRW x WCW waves; each wave RF*16 rows x CF*16 cols of 16x16x32 fragments.
template <int WRW, int WCW, int RF, int CF, int WCOLS, int NCR, int LSZ, bool BN_A>
__global__ __launch_bounds__(256, 1) void k_gemm_mfma(
    const float* __restrict__ H,
    const short* __restrict__ WtL, const short* __restrict__ WtR,
    const float* __restrict__ bias,
    const float* __restrict__ bnscale, const float* __restrict__ bnshift,
    float* __restrict__ yl, float* __restrict__ yr) {
    __shared__ short A_hi[128 * 128];
    __shared__ short A_lo[128 * 128];
    __shared__ short B_hi[WCOLS * 128];
    __shared__ short B_lo[WCOLS * 128];

    int tid = threadIdx.x;
    int row0 = blockIdx.x * 128;

    // ---- stage A (hi/lo split, optional BN+ReLU), 2048 chunks of 8 elems ----
#pragma unroll
    for (int i = 0; i < 8; ++i) {
        int c = tid + 256 * i;
        int r = c >> 4;
        int k0 = (c & 15) << 3;
        int gr = row0 + r;
        float f[8];
        if (gr < NNODES) {
            float4 v0 = *(const float4*)&H[(size_t)gr * CH + k0];
            float4 v1 = *(const float4*)&H[(size_t)gr * CH + k0 + 4];
            f[0] = v0.x; f[1] = v0.y; f[2] = v0.z; f[3] = v0.w;
            f[4] = v1.x; f[5] = v1.y; f[6] = v1.z; f[7] = v1.w;
        } else {
#pragma unroll
            for (int j = 0; j < 8; ++j) f[j] = 0.f;
        }
        if (BN_A) {
            float4 s0 = *(const float4*)&bnscale[k0];
            float4 s1 = *(const float4*)&bnscale[k0 + 4];
            float4 h0 = *(const float4*)&bnshift[k0];
            float4 h1 = *(const float4*)&bnshift[k0 + 4];
            f[0] = fmaxf(fmaf(f[0], s0.x, h0.x), 0.f);
            f[1] = fmaxf(fmaf(f[1], s0.y, h0.y), 0.f);
            f[2] = fmaxf(fmaf(f[2], s0.z, h0.z), 0.f);
            f[3] = fmaxf(fmaf(f[3], s0.w, h0.w), 0.f);
            f[4] = fmaxf(fmaf(f[4], s1.x, h1.x), 0.f);
            f[5] = fmaxf(fmaf(f[5], s1.y, h1.y), 0.f);
            f[6] = fmaxf(fmaf(f[6], s1.z, h1.z), 0.f);
            f[7] = fmaxf(fmaf(f[7], s1.w, h1.w), 0.f);
        }
        s8v hi8, lo8;
#pragma unroll
        for (int j = 0; j < 8; ++j) {
            unsigned short h = f2bf_rn(f[j]);
            hi8[j] = (short)h;
            lo8[j] = (short)f2bf_rn(f[j] - bf2f(h));
        }
        int e = ((r << 7) + k0) ^ ((r & 7) << 3);
        *(s8v*)&A_hi[e] = hi8;
        *(s8v*)&A_lo[e] = lo8;
    }

    int lane = tid & 63;
    int wid = tid >> 6;
    int wr = wid / WCW, wc = wid % WCW;
    int l15 = lane & 15, kb = lane >> 4;
    int rowbase = wr * RF * 16;
    int colbase = wc * CF * 16;

    for (int half = 0; half < 2; ++half) {
        if (half == 1) __syncthreads();  // drain half-0 LDS reads before W overwrite
        // ---- stage W^T tile (already bf16 hi/lo in global, just swizzle) ----
        const short* Wt = half ? WtR : WtL;
        constexpr int WCHUNK = WCOLS * 16;
#pragma unroll
        for (int i = 0; i < (WCHUNK + 255) / 256; ++i) {
            int c = tid + 256 * i;
            if (c < WCHUNK) {
                int col = c >> 4;
                int k0 = (c & 15) << 3;
                s8v hi8 = *(const s8v*)&Wt[col * 128 + k0];
                s8v lo8 = *(const s8v*)&Wt[LSZ + col * 128 + k0];
                int e = ((col << 7) + k0) ^ ((col & 7) << 3);
                *(s8v*)&B_hi[e] = hi8;
                *(s8v*)&B_lo[e] = lo8;
            }
        }
        __syncthreads();

        // ---- MFMA: acc += Ah*Bh + Al*Bh + Ah*Bl over K=128 ----
        f32x4 acc[RF][CF];
#pragma unroll
        for (int i = 0; i < RF; ++i)
#pragma unroll
            for (int j = 0; j < CF; ++j) acc[i][j] = (f32x4){0.f, 0.f, 0.f, 0.f};

#pragma unroll
        for (int ks = 0; ks < 4; ++ks) {
            s8v ah[RF], al[RF];
#pragma unroll
            for (int rf = 0; rf < RF; ++rf) {
                int r = rowbase + rf * 16 + l15;
                int e = ((r << 7) + ks * 32 + (kb << 3)) ^ ((r & 7) << 3);
                ah[rf] = *(const s8v*)&A_hi[e];
                al[rf] = *(const s8v*)&A_lo[e];
            }
#pragma unroll
            for (int cf = 0; cf < CF; ++cf) {
                int cc = colbase + cf * 16 + l15;
                int e = ((cc << 7) + ks * 32 + (kb << 3)) ^ ((cc & 7) << 3);
                s8v bh = *(const s8v*)&B_hi[e];
                s8v bl = *(const s8v*)&B_lo[e];
#pragma unroll
                for (int rf = 0; rf < RF; ++rf) {
                    acc[rf][cf] = __builtin_amdgcn_mfma_f32_16x16x32_bf16(ah[rf], bh, acc[rf][cf], 0, 0, 0);
                    acc[rf][cf] = __builtin_amdgcn_mfma_f32_16x16x32_bf16(al[rf], bh, acc[rf][cf], 0, 0, 0);
                    acc[rf][cf] = __builtin_amdgcn_mfma_f32_16x16x32_bf16(ah[rf], bl, acc[rf][cf], 0, 0, 0);
                }
            }
        }

        // ---- epilogue: C/D layout col=lane&15, row=(lane>>4)*4+reg (m89) ----
        float* Y = half ? yr : yl;
#pragma unroll
        for (int cf = 0; cf < CF; ++cf) {
            int gcol = colbase + cf * 16 + l15;
            float bb = 0.f;
            if (half == 1 && gcol < NCR) bb = bias[gcol];
#pragma unroll
            for (int rf = 0; rf < RF; ++rf) {
#pragma unroll
                for (int r = 0; r < 4; ++r) {
                    int grow = row0 + rowbase + rf * 16 + (lane >> 4) * 4 + r;
                    if (grow < NNODES && gcol < NCR)
                        Y[(size_t)grow * NCR + gcol] = acc[rf][cf][r] + bb;
                }
            }
        }
    }
}

// ---------------- combine (NC=128): z[n] += invdeg[n] * sum yl[src] ----------------
__global__ void k_combine128(const float* __restrict__ yl, const int* __restrict__ row_ptr,
                             const int* __restrict__ sorted_src, const float* __restrict__ inv_deg,
                             float* __restrict__ z) {
    int wave = threadIdx.x >> 6, lane = threadIdx.x & 63;
    int node = blockIdx.x * 4 + wave;
    if (node >= NNODES) return;
    int s0 = row_ptr[node], s1 = row_ptr[node + 1];
    const float2* Y = (const float2*)yl;
    float ax0 = 0.f, ay0 = 0.f, ax1 = 0.f, ay1 = 0.f;
    float ax2 = 0.f, ay2 = 0.f, ax3 = 0.f, ay3 = 0.f;
    int e = s0;
    for (; e + 4 <= s1; e += 4) {
        int i0 = sorted_src[e], i1 = sorted_src[e + 1];
        int i2 = sorted_src[e + 2], i3 = sorted_src[e + 3];
        float2 v0 = Y[(size_t)i0 * 64 + lane];
        float2 v1 = Y[(size_t)i1 * 64 + lane];
        float2 v2 = Y[(size_t)i2 * 64 + lane];
        float2 v3 = Y[(size_t)i3 * 64 + lane];
        ax0 += v0.x; ay0 += v0.y; ax1 += v1.x; ay1 += v1.y;
        ax2 += v2.x; ay2 += v2.y; ax3 += v3.x; ay3 += v3.y;
    }
    for (; e < s1; ++e) {
        int i = sorted_src[e];
        float2 v = Y[(size_t)i * 64 + lane];
        ax0 += v.x; ay0 += v.y;
    }
    float w = inv_deg[node];
    float2* Z = (float2*)z;
    float2 r = Z[(size_t)node * 64 + lane];
    r.x += (ax0 + ax1 + ax2 + ax3) * w;
    r.y += (ay0 + ay1 + ay2 + ay3) * w;
    Z[(size_t)node * 64 + lane] = r;
}

// ---------------- combine (NC=40) + log_softmax -> out ----------------
__global__ void k_combine40_lsm(const float* __restrict__ yl, const float* __restrict__ yr,
                                const int* __restrict__ row_ptr, const int* __restrict__ sorted_src,
                                const float* __restrict__ inv_deg, float* __restrict__ out) {
    int wave = threadIdx.x >> 6, lane = threadIdx.x & 63;
    int node = blockIdx.x * 4 + wave;
    if (node >= NNODES) return;
    bool act = lane < 20;
    int s0 = row_ptr[node], s1 = row_ptr[node + 1];
    float ax0 = 0.f, ay0 = 0.f, ax1 = 0.f, ay1 = 0.f;
    float ax2 = 0.f, ay2 = 0.f, ax3 = 0.f, ay3 = 0.f;
    int e = s0;
    for (; e + 4 <= s1; e += 4) {
        int i0 = sorted_src[e], i1 = sorted_src[e + 1];
        int i2 = sorted_src[e + 2], i3 = sorted_src[e + 3];
        if (act) {
            float2 v0 = *(const float2*)&yl[(size_t)i0 * OUTC + lane * 2];
            float2 v1 = *(const float2*)&yl[(size_t)i1 * OUTC + lane * 2];
            float2 v2 = *(const float2*)&yl[(size_t)i2 * OUTC + lane * 2];
            float2 v3 = *(const float2*)&yl[(size_t)i3 * OUTC + lane * 2];
            ax0 += v0.x; ay0 += v0.y; ax1 += v1.x; ay1 += v1.y;
            ax2 += v2.x; ay2 += v2.y; ax3 += v3.x; ay3 += v3.y;
        }
    }
    for (; e < s1; ++e) {
        int i = sorted_src[e];
        if (act) {
            float2 v = *(const float2*)&yl[(size_t)i * OUTC + lane * 2];
            ax0 += v.x; ay0 += v.y;
        }
    }
    float zx = 0.f, zy = 0.f;
    if (act) {
        float w = inv_deg[node];
        float2 r = *(const float2*)&yr[(size_t)node * OUTC + lane * 2];
        zx = (ax0 + ax1 + ax2 + ax3) * w + r.x;
        zy = (ay0 + ay1 + ay2 + ay3) * w + r.y;
    }
    float m = act ? fmaxf(zx, zy) : -INFINITY;
#pragma unroll
    for (int off = 1; off <= 16; off <<= 1) m = fmaxf(m, __shfl_xor(m, off));
    float se = act ? (expf(zx - m) + expf(zy - m)) : 0.f;
#pragma unroll
    for (int off = 1; off <= 16; off <<= 1) se += __shfl_xor(se, off);
    float lse = m + logf(se);
    if (act) {
        float2 o = make_float2(zx - lse, zy - lse);
        *(float2*)&out[(size_t)node * OUTC + lane * 2] = o;
    }
}

// ---------------- BN batch stats (sum, sumsq per channel) ----------------
__global__ void k_stats(const float* __restrict__ h, float* __restrict__ sums) {
    __shared__ float ls[256], ls2[256];
    int c = threadIdx.x & 127;
    int half = threadIdx.x >> 7;
    float s = 0.f, s2 = 0.f;
    for (int r = blockIdx.x * 2 + half; r < NNODES; r += gridDim.x * 2) {
        float v = h[(size_t)r * CH + c];
        s += v; s2 += v * v;
    }
    ls[threadIdx.x] = s; ls2[threadIdx.x] = s2;
    __syncthreads();
    if (half == 0) {
        atomicAdd(&sums[c], ls[c] + ls[c + 128]);
        atomicAdd(&sums[CH + c], ls2[c] + ls2[c + 128]);
    }
}

__global__ void k_bn_finalize(const float* __restrict__ sums, const float* __restrict__ g,
                              const float* __restrict__ be, float* __restrict__ scale,
                              float* __restrict__ shift) {
    int c = threadIdx.x;
    if (c < CH) {
        float mean = sums[c] * (1.0f / NNODES);
        float var = sums[128 + c] * (1.0f / NNODES) - mean * mean;
        float sc = g[c] * rsqrtf(var + BN_EPS);
        scale[c] = sc;
        shift[c] = be[c] - mean * sc;
    }
}

extern "C" void kernel_launch(void* const* d_in, const int* in_sizes, int n_in,
                              void* d_out, int out_size, void* d_ws, size_t ws_size,
                              hipStream_t stream) {
    const float* x   = (const float*)d_in[0];
    const int* esrc  = (const int*)d_in[1];
    const int* edst  = (const int*)d_in[2];
    const float* W_l0 = (const float*)d_in[3];
    const float* b_l0 = (const float*)d_in[4];
    const float* W_r0 = (const float*)d_in[5];
    const float* g0   = (const float*)d_in[6];
    const float* be0  = (const float*)d_in[7];
    const float* W_l1 = (const float*)d_in[8];
    const float* b_l1 = (const float*)d_in[9];
    const float* W_r1 = (const float*)d_in[10];
    const float* g1   = (const float*)d_in[11];
    const float* be1  = (const float*)d_in[12];
    const float* W_l2 = (const float*)d_in[13];
    const float* b_l2 = (const float*)d_in[14];
    const float* W_r2 = (const float*)d_in[15];
    float* out = (float*)d_out;

    char* w = (char*)d_ws;
    size_t o = 0;
    auto nxt = [&](size_t b) { void* p = w + o; o = (o + b + 511) & ~(size_t)511; return p; };
    int* deg      = (int*)nxt((size_t)NNODES * 4);
    int* row_ptr  = (int*)nxt((size_t)(NNODES + 1) * 4);
    int* cursor   = (int*)nxt((size_t)NNODES * 4);
    float* invdeg = (float*)nxt((size_t)NNODES * 4);
    int* blkSums  = (int*)nxt(128 * 4);
    float* sums   = (float*)nxt(512 * 4);
    float* scsh   = (float*)nxt(512 * 4);
    short* wtbuf  = (short*)nxt(155648 * 2);   // prepped W^T hi/lo bf16
    int* sorted   = (int*)nxt((size_t)NEDGES * 4);
    float* ylbuf  = (float*)nxt((size_t)NNODES * CH * 4);
    float* zA     = (float*)nxt((size_t)NNODES * CH * 4);  // z0, later yr2
    float* zB     = (float*)nxt((size_t)NNODES * CH * 4);  // z1
    float* sums0 = sums, *sums1 = sums + 256;
    float* scale0 = scsh, *shift0 = scsh + 128, *scale1 = scsh + 256, *shift1 = scsh + 384;

    const short* wtL0 = wtbuf;
    const short* wtR0 = wtbuf + 32768;
    const short* wtL1 = wtbuf + 65536;
    const short* wtR1 = wtbuf + 98304;
    const short* wtL2 = wtbuf + 131072;
    const short* wtR2 = wtbuf + 143360;

    hipMemsetAsync(deg, 0, (size_t)NNODES * 4, stream);
    hipMemsetAsync(sums, 0, 512 * 4, stream);

    const int EB = (NEDGES + 255) / 256;
    const int SCAN_B = (NNODES + 1023) / 1024;
    const int NB = (NNODES + 255) / 256;
    const int COMB_B = (NNODES + 3) / 4;
    const int GEMM_B = (NNODES + 127) / 128;  // 782

    // W prep + CSR build
    k_prepw<<<304, 256, 0, stream>>>(W_l0, W_r0, W_l1, W_r1, W_l2, W_r2, wtbuf);
    k_deg<<<EB, 256, 0, stream>>>(edst, deg);
    k_scan1<<<SCAN_B, 256, 0, stream>>>(deg, row_ptr, blkSums, invdeg);
    k_scan2<<<1, 64, 0, stream>>>(blkSums, SCAN_B);
    k_scan3<<<NB, 256, 0, stream>>>(row_ptr, cursor, blkSums);
    k_fill<<<EB, 256, 0, stream>>>(esrc, edst, cursor, sorted);

    // layer 0
    k_gemm_mfma<2, 2, 4, 4, 128, 128, 16384, false><<<GEMM_B, 256, 0, stream>>>(
        x, wtL0, wtR0, b_l0, nullptr, nullptr, ylbuf, zA);
    k_combine128<<<COMB_B, 256, 0, stream>>>(ylbuf, row_ptr, sorted, invdeg, zA);
    k_stats<<<256, 256, 0, stream>>>(zA, sums0);
    k_bn_finalize<<<1, 128, 0, stream>>>(sums0, g0, be0, scale0, shift0);

    // layer 1
    k_gemm_mfma<2, 2, 4, 4, 128, 128, 16384, true><<<GEMM_B, 256, 0, stream>>>(
        zA, wtL1, wtR1, b_l1, scale0, shift0, ylbuf, zB);
    k_combine128<<<COMB_B, 256, 0, stream>>>(ylbuf, row_ptr, sorted, invdeg, zB);
    k_stats<<<256, 256, 0, stream>>>(zB, sums1);
    k_bn_finalize<<<1, 128, 0, stream>>>(sums1, g1, be1, scale1, shift1);

    // layer 2: 4x1 waves, each 32 rows x 48 cols (cols 40-47 padded zero)
    k_gemm_mfma<4, 1, 2, 3, 48, 40, 6144, true><<<GEMM_B, 256, 0, stream>>>(
        zB, wtL2, wtR2, b_l2, scale1, shift1, ylbuf, zA);
    k_combine40_lsm<<<COMB_B, 256, 0, stream>>>(ylbuf, zA, row_ptr, sorted, invdeg, out);
}